// Round 3
// baseline (249.314 us; speedup 1.0000x reference)
//
#include <hip/hip_runtime.h>
#include <hip/hip_bf16.h>

#define NNODES 4096
#define CAP 256

// ---------------------------------------------------------------------------
// Edge extraction: mask row -> column list (deterministic order via prefix scan)
// ---------------------------------------------------------------------------
__global__ __launch_bounds__(256) void edge_build_kernel(
    const float* __restrict__ mask, int* __restrict__ deg, int* __restrict__ cols) {
  const int n = blockIdx.x;
  const int tid = threadIdx.x;
  const int lane = tid & 63, wid = tid >> 6;
  const float4* row = (const float4*)(mask + (size_t)n * NNODES);
  float4 v[4];
  int cnt = 0;
#pragma unroll
  for (int j = 0; j < 4; ++j) {
    v[j] = row[tid + 256 * j];  // coalesced
    cnt += (v[j].x == 0.0f) + (v[j].y == 0.0f) + (v[j].z == 0.0f) + (v[j].w == 0.0f);
  }
  int x = cnt;
#pragma unroll
  for (int o = 1; o < 64; o <<= 1) {
    int y = __shfl_up(x, o);
    if (lane >= o) x += y;
  }
  __shared__ int wsum[4];
  if (lane == 63) wsum[wid] = x;
  __syncthreads();
  int base = 0;
  for (int w = 0; w < wid; ++w) base += wsum[w];
  int off = base + x - cnt;
  if (tid == 0) {
    int total = wsum[0] + wsum[1] + wsum[2] + wsum[3];
    deg[n] = total < CAP ? total : CAP;
  }
  int* dst = cols + (size_t)n * CAP;
#pragma unroll
  for (int j = 0; j < 4; ++j) {
    const int c0 = (tid + 256 * j) * 4;
    float fv[4] = {v[j].x, v[j].y, v[j].z, v[j].w};
#pragma unroll
    for (int k = 0; k < 4; ++k) {
      if (fv[k] == 0.0f) {
        if (off < CAP) dst[off] = c0 + k;
        ++off;
      }
    }
  }
}

// ---------------------------------------------------------------------------
// fp32 GEMM, 32x64 output tile per block, whole KC-slab staged once in LDS,
// single __syncthreads, fully-unrolled inner loop, broadcast-only LDS reads.
// Split-K via blockIdx.z: each z writes its own partial plane of C.
// grid: (M/32, N/64, K/KC)
// ---------------------------------------------------------------------------
template <int KC>
__global__ __launch_bounds__(256) void gemm32x64_kernel(
    const float* __restrict__ A, int lda, const float* __restrict__ W, int ldw,
    const float* __restrict__ bias, float* __restrict__ C, int ldc) {
  __shared__ float As[32][KC];
  __shared__ float Ws[KC][64];
  const int t = threadIdx.x;
  const int brow = blockIdx.x * 32;
  const int bcol = blockIdx.y * 64;
  const int k0 = blockIdx.z * KC;
  C += (size_t)blockIdx.z * gridDim.x * 32 * ldc;  // split-K partial plane
  // stage A tile: 32 rows x KC (row-contiguous, float4, coalesced)
  for (int i = t; i < 32 * (KC / 4); i += 256) {
    int r = i / (KC / 4), k4 = (i % (KC / 4)) * 4;
    *(float4*)&As[r][k4] = *(const float4*)&A[(size_t)(brow + r) * lda + k0 + k4];
  }
  // stage W tile: KC rows x 64 cols (coalesced 256B segments)
  for (int i = t; i < KC * 16; i += 256) {
    int k = i / 16, c4 = (i % 16) * 4;
    *(float4*)&Ws[k][c4] = *(const float4*)&W[(size_t)(k0 + k) * ldw + bcol + c4];
  }
  __syncthreads();
  const int tx = t & 31, ty = t >> 5;  // ty in [0,8): rows ty*4+i; cols tx, tx+32
  float acc[4][2] = {};
#pragma unroll
  for (int k = 0; k < KC; k += 4) {
    float4 a[4];
#pragma unroll
    for (int i = 0; i < 4; ++i) a[i] = *(const float4*)&As[ty * 4 + i][k];
#pragma unroll
    for (int kk = 0; kk < 4; ++kk) {
      float w0 = Ws[k + kk][tx], w1 = Ws[k + kk][tx + 32];
#pragma unroll
      for (int i = 0; i < 4; ++i) {
        float av = ((const float*)&a[i])[kk];
        acc[i][0] = fmaf(av, w0, acc[i][0]);
        acc[i][1] = fmaf(av, w1, acc[i][1]);
      }
    }
  }
  const float b0v = bias ? bias[bcol + tx] : 0.f;
  const float b1v = bias ? bias[bcol + tx + 32] : 0.f;
#pragma unroll
  for (int i = 0; i < 4; ++i) {
    const size_t r = brow + ty * 4 + i;
    C[r * ldc + bcol + tx] = acc[i][0] + b0v;
    C[r * ldc + bcol + tx + 32] = acc[i][1] + b1v;
  }
}

// sum 4 split-K partials + bias -> proj1 (float4-vectorized)
__global__ __launch_bounds__(256) void reduce4_bias_kernel(
    const float* __restrict__ part, const float* __restrict__ bias,
    float* __restrict__ out) {
  const int i = blockIdx.x * 256 + threadIdx.x;  // float4 idx, 65536 total
  const float4* p = (const float4*)part;
  float4 a = p[i], b = p[i + 65536], c = p[i + 131072], d = p[i + 196608];
  const float4 bb = *(const float4*)&bias[(i & 15) * 4];
  float4 r;
  r.x = a.x + b.x + c.x + d.x + bb.x;
  r.y = a.y + b.y + c.y + d.y + bb.y;
  r.z = a.z + b.z + c.z + d.z + bb.z;
  r.w = a.w + b.w + c.w + d.w + bb.w;
  ((float4*)out)[i] = r;
}

// ---------------------------------------------------------------------------
// s_src[n,h] = sum_f proj[n,h,f]*a_src[h,f]; s_tgt likewise. One wave per (n,h).
// ---------------------------------------------------------------------------
__global__ __launch_bounds__(256) void scores_kernel(
    const float* __restrict__ proj, const float* __restrict__ a_src,
    const float* __restrict__ a_tgt, float* __restrict__ s_src,
    float* __restrict__ s_tgt, int H) {
  const int g = blockIdx.x * 4 + (threadIdx.x >> 6);
  const int lane = threadIdx.x & 63;
  const int n = g / H, h = g - n * H;
  if (n >= NNODES) return;
  float p = proj[(size_t)n * (H * 64) + h * 64 + lane];
  float vs = p * a_src[h * 64 + lane];
  float vt = p * a_tgt[h * 64 + lane];
#pragma unroll
  for (int o = 32; o; o >>= 1) {
    vs += __shfl_down(vs, o);
    vt += __shfl_down(vt, o);
  }
  if (lane == 0) {
    s_src[(size_t)n * H + h] = vs;
    s_tgt[(size_t)n * H + h] = vt;
  }
}

// ---------------------------------------------------------------------------
// Sparse attention row: softmax over edges (== masked dense softmax in fp32
// since exp(-1e9) underflows to 0), then out[n,:] = sum_e w_e * proj[m_e,:]
// ---------------------------------------------------------------------------
template <int H>
__global__ void attn_kernel(
    const float* __restrict__ proj, const float* __restrict__ s_src,
    const float* __restrict__ s_tgt, const int* __restrict__ deg,
    const int* __restrict__ cols, float* __restrict__ out) {
  constexpr int F = 64;
  const int n = blockIdx.x;
  const int tid = threadIdx.x;
  const int nt = blockDim.x;
  __shared__ int sm_[CAP];
  __shared__ float sw[CAP * H];
  __shared__ float sinv[H];
  const int d = deg[n];
  for (int i = tid; i < d; i += nt) sm_[i] = cols[(size_t)n * CAP + i];
  __syncthreads();
  for (int i = tid; i < d * H; i += nt) {
    int e = i / H, h = i % H;
    float s = s_src[n * H + h] + s_tgt[sm_[e] * H + h];
    sw[i] = s >= 0.f ? s : 0.2f * s;
  }
  __syncthreads();
  const int lane = tid & 63, wid = tid >> 6, nw = (nt >> 6) ? (nt >> 6) : 1;
  for (int h = wid; h < H; h += nw) {
    float mx = -1e30f;
    for (int e = lane; e < d; e += 64) mx = fmaxf(mx, sw[e * H + h]);
#pragma unroll
    for (int o = 32; o; o >>= 1) mx = fmaxf(mx, __shfl_xor(mx, o));
    float sum = 0.f;
    for (int e = lane; e < d; e += 64) {
      float w = __expf(sw[e * H + h] - mx);
      sw[e * H + h] = w;
      sum += w;
    }
#pragma unroll
    for (int o = 32; o; o >>= 1) sum += __shfl_xor(sum, o);
    if (lane == 0) sinv[h] = 1.0f / sum;
  }
  __syncthreads();
  for (int o = tid; o < H * F; o += nt) {
    const int h = o >> 6;
    float acc = 0.f;
    for (int e = 0; e < d; ++e)
      acc = fmaf(sw[e * H + h], proj[(size_t)sm_[e] * (H * F) + o], acc);
    out[(size_t)n * (H * F) + o] = acc * sinv[h];
  }
}

// ---------------------------------------------------------------------------
extern "C" void kernel_launch(void* const* d_in, const int* in_sizes, int n_in,
                              void* d_out, int out_size, void* d_ws, size_t ws_size,
                              hipStream_t stream) {
  const float* x      = (const float*)d_in[0];
  const float* mask   = (const float*)d_in[1];
  const float* W0     = (const float*)d_in[2];
  const float* b0     = (const float*)d_in[3];
  const float* a_src0 = (const float*)d_in[4];
  const float* a_tgt0 = (const float*)d_in[5];
  const float* W1     = (const float*)d_in[6];
  const float* b1     = (const float*)d_in[7];
  const float* a_src1 = (const float*)d_in[8];
  const float* a_tgt1 = (const float*)d_in[9];
  float* out = (float*)d_out;

  // workspace layout (~22.3 MB)
  float* ws    = (float*)d_ws;
  float* proj0 = ws;                          // 4096*512 (dead after attn0 -> reused as split-K partials)
  float* h0    = proj0 + NNODES * 512;        // 4096*512
  float* proj1 = h0 + NNODES * 512;           // 4096*64
  float* ssrc0 = proj1 + NNODES * 64;         // 4096*8
  float* stgt0 = ssrc0 + NNODES * 8;          // 4096*8
  float* ssrc1 = stgt0 + NNODES * 8;          // 4096
  float* stgt1 = ssrc1 + NNODES;              // 4096
  int* deg  = (int*)(stgt1 + NNODES);         // 4096
  int* cols = deg + NNODES;                   // 4096*CAP
  float* part = proj0;                        // 4*4096*64 aliases proj0 (dead by then)

  edge_build_kernel<<<NNODES, 256, 0, stream>>>(mask, deg, cols);

  // ---- layer 0 (H=8, F=64): K=128 whole-slab, grid 128x8 ----
  gemm32x64_kernel<128><<<dim3(NNODES / 32, 8, 1), 256, 0, stream>>>(
      x, 128, W0, 512, b0, proj0, 512);
  scores_kernel<<<(NNODES * 8) / 4, 256, 0, stream>>>(proj0, a_src0, a_tgt0,
                                                      ssrc0, stgt0, 8);
  attn_kernel<8><<<NNODES, 256, 0, stream>>>(proj0, ssrc0, stgt0, deg, cols, h0);

  // ---- layer 1 (H=1, F=64): K=512 split-K by 4 + reduce ----
  gemm32x64_kernel<128><<<dim3(NNODES / 32, 1, 4), 256, 0, stream>>>(
      h0, 512, W1, 64, nullptr, part, 64);
  reduce4_bias_kernel<<<256, 256, 0, stream>>>(part, b1, proj1);
  scores_kernel<<<NNODES / 4, 256, 0, stream>>>(proj1, a_src1, a_tgt1,
                                                ssrc1, stgt1, 1);
  attn_kernel<1><<<NNODES, 64, 0, stream>>>(proj1, ssrc1, stgt1, deg, cols, out);
}

// Round 5
// 88.125 us; speedup vs baseline: 2.8291x; 2.8291x over previous
//
#include <hip/hip_runtime.h>
#include <hip/hip_bf16.h>

#define NNODES 4096
#define CAP 256

// ---------------------------------------------------------------------------
// Edge extraction: mask row -> column list (deterministic order via prefix scan)
// ---------------------------------------------------------------------------
__global__ __launch_bounds__(256) void edge_build_kernel(
    const float* __restrict__ mask, int* __restrict__ deg, int* __restrict__ cols) {
  const int n = blockIdx.x;
  const int tid = threadIdx.x;
  const int lane = tid & 63, wid = tid >> 6;
  const float4* row = (const float4*)(mask + (size_t)n * NNODES);
  float4 v[4];
  int cnt = 0;
#pragma unroll
  for (int j = 0; j < 4; ++j) {
    v[j] = row[tid + 256 * j];  // coalesced
    cnt += (v[j].x == 0.0f) + (v[j].y == 0.0f) + (v[j].z == 0.0f) + (v[j].w == 0.0f);
  }
  int x = cnt;
#pragma unroll
  for (int o = 1; o < 64; o <<= 1) {
    int y = __shfl_up(x, o);
    if (lane >= o) x += y;
  }
  __shared__ int wsum[4];
  if (lane == 63) wsum[wid] = x;
  __syncthreads();
  int base = 0;
  for (int w = 0; w < wid; ++w) base += wsum[w];
  int off = base + x - cnt;
  if (tid == 0) {
    int total = wsum[0] + wsum[1] + wsum[2] + wsum[3];
    deg[n] = total < CAP ? total : CAP;
  }
  int* dst = cols + (size_t)n * CAP;
#pragma unroll
  for (int j = 0; j < 4; ++j) {
    const int c0 = (tid + 256 * j) * 4;
    float fv[4] = {v[j].x, v[j].y, v[j].z, v[j].w};
#pragma unroll
    for (int k = 0; k < 4; ++k) {
      if (fv[k] == 0.0f) {
        if (off < CAP) dst[off] = c0 + k;
        ++off;
      }
    }
  }
}

// ---------------------------------------------------------------------------
// fp32 GEMM, 32x64 tile, KZ=128 per block (z = split-K plane), BK=32 chunks.
// 2x4 register blocking. A-fragment LDS reads are wave-broadcast (tx-invariant);
// W stays k-major (natural row-major W[k][n]) so staging needs no transpose.
// #pragma unroll 2 keeps the live set bounded (R3 lesson: full unroll -> 256
// VGPR + 400MB scratch spill traffic).
// grid: (M/32, N/64, K/128)
// ---------------------------------------------------------------------------
__global__ __launch_bounds__(256) void gemm32x64_v2(
    const float* __restrict__ A, int lda, const float* __restrict__ W, int ldw,
    const float* __restrict__ bias, float* __restrict__ C, int ldc) {
  __shared__ float As[32][36];  // +4 pad keeps rows 16B-aligned, spreads banks
  __shared__ float Ws[32][64];
  const int t = threadIdx.x;
  const int brow = blockIdx.x * 32;
  const int bcol = blockIdx.y * 64;
  const int k0base = blockIdx.z * 128;
  C += (size_t)blockIdx.z * gridDim.x * 32 * ldc;  // split-K partial plane
  const int tx = t & 15, ty = t >> 4;  // cols tx*4..+3, rows ty*2..+1
  const int ar = t >> 3, ak = (t & 7) * 4;  // A staging: 1 float4/thread
  float acc[2][4] = {};
  for (int c = 0; c < 4; ++c) {
    const int k0 = k0base + c * 32;
    // stage A: 32 rows x 32 k (coalesced float4)
    *(float4*)&As[ar][ak] = *(const float4*)&A[(size_t)(brow + ar) * lda + k0 + ak];
    // stage W: 32 k x 64 cols (coalesced float4, 2 per thread)
#pragma unroll
    for (int q = 0; q < 2; ++q) {
      int i = t + q * 256;
      int k = i >> 4, c4 = (i & 15) * 4;
      *(float4*)&Ws[k][c4] = *(const float4*)&W[(size_t)(k0 + k) * ldw + bcol + c4];
    }
    __syncthreads();
#pragma unroll 2
    for (int kk = 0; kk < 32; kk += 4) {
      float4 a0 = *(const float4*)&As[ty * 2 + 0][kk];
      float4 a1 = *(const float4*)&As[ty * 2 + 1][kk];
#pragma unroll
      for (int j = 0; j < 4; ++j) {
        float4 w = *(const float4*)&Ws[kk + j][tx * 4];
        float av0 = ((const float*)&a0)[j];
        float av1 = ((const float*)&a1)[j];
        acc[0][0] = fmaf(av0, w.x, acc[0][0]);
        acc[0][1] = fmaf(av0, w.y, acc[0][1]);
        acc[0][2] = fmaf(av0, w.z, acc[0][2]);
        acc[0][3] = fmaf(av0, w.w, acc[0][3]);
        acc[1][0] = fmaf(av1, w.x, acc[1][0]);
        acc[1][1] = fmaf(av1, w.y, acc[1][1]);
        acc[1][2] = fmaf(av1, w.z, acc[1][2]);
        acc[1][3] = fmaf(av1, w.w, acc[1][3]);
      }
    }
    __syncthreads();
  }
  float4 bv = make_float4(0.f, 0.f, 0.f, 0.f);
  if (bias) bv = *(const float4*)&bias[bcol + tx * 4];
#pragma unroll
  for (int r = 0; r < 2; ++r) {
    float4 o;
    o.x = acc[r][0] + bv.x; o.y = acc[r][1] + bv.y;
    o.z = acc[r][2] + bv.z; o.w = acc[r][3] + bv.w;
    *(float4*)&C[(size_t)(brow + ty * 2 + r) * ldc + bcol + tx * 4] = o;
  }
}

// sum 4 split-K partials + bias -> proj1 (float4-vectorized)
__global__ __launch_bounds__(256) void reduce4_bias_kernel(
    const float* __restrict__ part, const float* __restrict__ bias,
    float* __restrict__ out) {
  const int i = blockIdx.x * 256 + threadIdx.x;  // float4 idx, 65536 total
  const float4* p = (const float4*)part;
  float4 a = p[i], b = p[i + 65536], c = p[i + 131072], d = p[i + 196608];
  const float4 bb = *(const float4*)&bias[(i & 15) * 4];
  float4 r;
  r.x = a.x + b.x + c.x + d.x + bb.x;
  r.y = a.y + b.y + c.y + d.y + bb.y;
  r.z = a.z + b.z + c.z + d.z + bb.z;
  r.w = a.w + b.w + c.w + d.w + bb.w;
  ((float4*)out)[i] = r;
}

// ---------------------------------------------------------------------------
// s_src[n,h] = sum_f proj[n,h,f]*a_src[h,f]; s_tgt likewise. One wave per (n,h).
// ---------------------------------------------------------------------------
__global__ __launch_bounds__(256) void scores_kernel(
    const float* __restrict__ proj, const float* __restrict__ a_src,
    const float* __restrict__ a_tgt, float* __restrict__ s_src,
    float* __restrict__ s_tgt, int H) {
  const int g = blockIdx.x * 4 + (threadIdx.x >> 6);
  const int lane = threadIdx.x & 63;
  const int n = g / H, h = g - n * H;
  if (n >= NNODES) return;
  float p = proj[(size_t)n * (H * 64) + h * 64 + lane];
  float vs = p * a_src[h * 64 + lane];
  float vt = p * a_tgt[h * 64 + lane];
#pragma unroll
  for (int o = 32; o; o >>= 1) {
    vs += __shfl_down(vs, o);
    vt += __shfl_down(vt, o);
  }
  if (lane == 0) {
    s_src[(size_t)n * H + h] = vs;
    s_tgt[(size_t)n * H + h] = vt;
  }
}

// ---------------------------------------------------------------------------
// Sparse attention row: softmax over edges (== masked dense softmax in fp32
// since exp(-1e9) underflows to 0), then out[n,:] = sum_e w_e * proj[m_e,:]
// ---------------------------------------------------------------------------
template <int H>
__global__ void attn_kernel(
    const float* __restrict__ proj, const float* __restrict__ s_src,
    const float* __restrict__ s_tgt, const int* __restrict__ deg,
    const int* __restrict__ cols, float* __restrict__ out) {
  constexpr int F = 64;
  const int n = blockIdx.x;
  const int tid = threadIdx.x;
  const int nt = blockDim.x;
  __shared__ int sm_[CAP];
  __shared__ float sw[CAP * H];
  __shared__ float sinv[H];
  const int d = deg[n];
  for (int i = tid; i < d; i += nt) sm_[i] = cols[(size_t)n * CAP + i];
  __syncthreads();
  for (int i = tid; i < d * H; i += nt) {
    int e = i / H, h = i % H;
    float s = s_src[n * H + h] + s_tgt[sm_[e] * H + h];
    sw[i] = s >= 0.f ? s : 0.2f * s;
  }
  __syncthreads();
  const int lane = tid & 63, wid = tid >> 6, nw = (nt >> 6) ? (nt >> 6) : 1;
  for (int h = wid; h < H; h += nw) {
    float mx = -1e30f;
    for (int e = lane; e < d; e += 64) mx = fmaxf(mx, sw[e * H + h]);
#pragma unroll
    for (int o = 32; o; o >>= 1) mx = fmaxf(mx, __shfl_xor(mx, o));
    float sum = 0.f;
    for (int e = lane; e < d; e += 64) {
      float w = __expf(sw[e * H + h] - mx);
      sw[e * H + h] = w;
      sum += w;
    }
#pragma unroll
    for (int o = 32; o; o >>= 1) sum += __shfl_xor(sum, o);
    if (lane == 0) sinv[h] = 1.0f / sum;
  }
  __syncthreads();
  for (int o = tid; o < H * F; o += nt) {
    const int h = o >> 6;
    float acc = 0.f;
    for (int e = 0; e < d; ++e)
      acc = fmaf(sw[e * H + h], proj[(size_t)sm_[e] * (H * F) + o], acc);
    out[(size_t)n * (H * F) + o] = acc * sinv[h];
  }
}

// ---------------------------------------------------------------------------
extern "C" void kernel_launch(void* const* d_in, const int* in_sizes, int n_in,
                              void* d_out, int out_size, void* d_ws, size_t ws_size,
                              hipStream_t stream) {
  const float* x      = (const float*)d_in[0];
  const float* mask   = (const float*)d_in[1];
  const float* W0     = (const float*)d_in[2];
  const float* b0     = (const float*)d_in[3];
  const float* a_src0 = (const float*)d_in[4];
  const float* a_tgt0 = (const float*)d_in[5];
  const float* W1     = (const float*)d_in[6];
  const float* b1     = (const float*)d_in[7];
  const float* a_src1 = (const float*)d_in[8];
  const float* a_tgt1 = (const float*)d_in[9];
  float* out = (float*)d_out;

  // workspace layout (~22.3 MB)
  float* ws    = (float*)d_ws;
  float* proj0 = ws;                          // 4096*512 (dead after attn0 -> reused as split-K partials)
  float* h0    = proj0 + NNODES * 512;        // 4096*512
  float* proj1 = h0 + NNODES * 512;           // 4096*64
  float* ssrc0 = proj1 + NNODES * 64;         // 4096*8
  float* stgt0 = ssrc0 + NNODES * 8;          // 4096*8
  float* ssrc1 = stgt0 + NNODES * 8;          // 4096
  float* stgt1 = ssrc1 + NNODES;              // 4096
  int* deg  = (int*)(stgt1 + NNODES);         // 4096
  int* cols = deg + NNODES;                   // 4096*CAP
  float* part = proj0;                        // 4*4096*64 aliases proj0 (dead by then)

  edge_build_kernel<<<NNODES, 256, 0, stream>>>(mask, deg, cols);

  // ---- layer 0 (H=8, F=64): grid 128x8, K=128 in one z-plane ----
  gemm32x64_v2<<<dim3(NNODES / 32, 8, 1), 256, 0, stream>>>(
      x, 128, W0, 512, b0, proj0, 512);
  scores_kernel<<<(NNODES * 8) / 4, 256, 0, stream>>>(proj0, a_src0, a_tgt0,
                                                      ssrc0, stgt0, 8);
  attn_kernel<8><<<NNODES, 256, 0, stream>>>(proj0, ssrc0, stgt0, deg, cols, h0);

  // ---- layer 1 (H=1, F=64): K=512 split-K by 4 + reduce ----
  gemm32x64_v2<<<dim3(NNODES / 32, 1, 4), 256, 0, stream>>>(
      h0, 512, W1, 64, nullptr, part, 64);
  reduce4_bias_kernel<<<256, 256, 0, stream>>>(part, b1, proj1);
  scores_kernel<<<NNODES / 4, 256, 0, stream>>>(proj1, a_src1, a_tgt1,
                                                ssrc1, stgt1, 1);
  attn_kernel<1><<<NNODES, 64, 0, stream>>>(proj1, ssrc1, stgt1, deg, cols, out);
}

// Round 8
// 76.823 us; speedup vs baseline: 3.2453x; 1.1471x over previous
//
#include <hip/hip_runtime.h>
#include <hip/hip_bf16.h>

#define NNODES 4096
#define CAP 256

// ---------------------------------------------------------------------------
// Phase 1 (fused): blocks [0,4096) = edge extraction rows (HBM-bound);
// blocks [4096,5120) = layer-0 GEMM tiles + fused scores0 (VALU-bound).
// Merged so the mask scan overlaps the GEMM instead of serializing.
// ---------------------------------------------------------------------------
__global__ __launch_bounds__(256) void phase1_kernel(
    const float* __restrict__ mask, int* __restrict__ deg, int* __restrict__ cols,
    const float* __restrict__ x, const float* __restrict__ W0,
    const float* __restrict__ b0, const float* __restrict__ a_src0,
    const float* __restrict__ a_tgt0, float* __restrict__ proj0,
    float* __restrict__ ssrc0, float* __restrict__ stgt0) {
  __shared__ float smem[32 * 36 + 32 * 64];  // gemm tiles; edge path uses 4 ints
  const int t = threadIdx.x;
  if (blockIdx.x < NNODES) {
    // ---- edge extraction: mask row -> column list (prefix-scan compaction) ----
    const int n = blockIdx.x;
    const int lane = t & 63, wid = t >> 6;
    int* wsum = (int*)smem;
    const float4* row = (const float4*)(mask + (size_t)n * NNODES);
    float4 v[4];
    int cnt = 0;
#pragma unroll
    for (int j = 0; j < 4; ++j) {
      v[j] = row[t + 256 * j];  // coalesced
      cnt += (v[j].x == 0.0f) + (v[j].y == 0.0f) + (v[j].z == 0.0f) + (v[j].w == 0.0f);
    }
    int xs = cnt;
#pragma unroll
    for (int o = 1; o < 64; o <<= 1) {
      int y = __shfl_up(xs, o);
      if (lane >= o) xs += y;
    }
    if (lane == 63) wsum[wid] = xs;
    __syncthreads();
    int base = 0;
    for (int w = 0; w < wid; ++w) base += wsum[w];
    int off = base + xs - cnt;
    if (t == 0) {
      int total = wsum[0] + wsum[1] + wsum[2] + wsum[3];
      deg[n] = total < CAP ? total : CAP;
    }
    int* dst = cols + (size_t)n * CAP;
#pragma unroll
    for (int j = 0; j < 4; ++j) {
      const int c0 = (t + 256 * j) * 4;
      float fv[4] = {v[j].x, v[j].y, v[j].z, v[j].w};
#pragma unroll
      for (int k = 0; k < 4; ++k) {
        if (fv[k] == 0.0f) {
          if (off < CAP) dst[off] = c0 + k;
          ++off;
        }
      }
    }
  } else {
    // ---- gemm0: 32x64 tile, K=128 whole, BK=32 chunks (R3 lesson: bounded
    // unroll, ~56 VGPR, no spill) + fused scores0 epilogue ----
    float(*As)[36] = (float(*)[36])smem;
    float(*Ws)[64] = (float(*)[64])(smem + 32 * 36);
    const int bx = blockIdx.x - NNODES;
    const int brow = (bx & 127) * 32;
    const int head = bx >> 7;
    const int bcol = head * 64;
    const int tx = t & 15, ty = t >> 4;       // cols tx*4..+3, rows ty*2..+1
    const int ar = t >> 3, ak = (t & 7) * 4;  // A staging: 1 float4/thread
    float acc[2][4] = {};
    for (int c = 0; c < 4; ++c) {
      const int k0 = c * 32;
      *(float4*)&As[ar][ak] = *(const float4*)&x[(size_t)(brow + ar) * 128 + k0 + ak];
#pragma unroll
      for (int q = 0; q < 2; ++q) {
        int i = t + q * 256;
        int k = i >> 4, c4 = (i & 15) * 4;
        *(float4*)&Ws[k][c4] = *(const float4*)&W0[(size_t)(k0 + k) * 512 + bcol + c4];
      }
      __syncthreads();
#pragma unroll 2
      for (int kk = 0; kk < 32; kk += 4) {
        float4 a0 = *(const float4*)&As[ty * 2 + 0][kk];
        float4 a1 = *(const float4*)&As[ty * 2 + 1][kk];
#pragma unroll
        for (int j = 0; j < 4; ++j) {
          float4 w = *(const float4*)&Ws[kk + j][tx * 4];
          float av0 = ((const float*)&a0)[j];
          float av1 = ((const float*)&a1)[j];
          acc[0][0] = fmaf(av0, w.x, acc[0][0]);
          acc[0][1] = fmaf(av0, w.y, acc[0][1]);
          acc[0][2] = fmaf(av0, w.z, acc[0][2]);
          acc[0][3] = fmaf(av0, w.w, acc[0][3]);
          acc[1][0] = fmaf(av1, w.x, acc[1][0]);
          acc[1][1] = fmaf(av1, w.y, acc[1][1]);
          acc[1][2] = fmaf(av1, w.z, acc[1][2]);
          acc[1][3] = fmaf(av1, w.w, acc[1][3]);
        }
      }
      __syncthreads();
    }
    const float4 bv = *(const float4*)&b0[bcol + tx * 4];
    const float4 as = *(const float4*)&a_src0[head * 64 + tx * 4];
    const float4 at = *(const float4*)&a_tgt0[head * 64 + tx * 4];
#pragma unroll
    for (int r = 0; r < 2; ++r) {
      float4 o;
      o.x = acc[r][0] + bv.x; o.y = acc[r][1] + bv.y;
      o.z = acc[r][2] + bv.z; o.w = acc[r][3] + bv.w;
      const size_t node = brow + ty * 2 + r;
      *(float4*)&proj0[node * 512 + bcol + tx * 4] = o;
      // fused scores0: 16-lane reduce over f (tx segments are 16-aligned in wave)
      float ps = o.x * as.x + o.y * as.y + o.z * as.z + o.w * as.w;
      float pt = o.x * at.x + o.y * at.y + o.z * at.z + o.w * at.w;
#pragma unroll
      for (int m = 8; m; m >>= 1) {
        ps += __shfl_xor(ps, m);
        pt += __shfl_xor(pt, m);
      }
      if (tx == 0) {
        ssrc0[node * 8 + head] = ps;
        stgt0[node * 8 + head] = pt;
      }
    }
  }
}

// ---------------------------------------------------------------------------
// fp32 GEMM, 32x64 tile, 128-K per z-plane, BK=32 chunks, 2x4 reg blocking.
// Used for layer 1 (split-K by 4, bias deferred to reduce). grid (M/32,N/64,K/128)
// ---------------------------------------------------------------------------
__global__ __launch_bounds__(256) void gemm32x64_v2(
    const float* __restrict__ A, int lda, const float* __restrict__ W, int ldw,
    float* __restrict__ C, int ldc) {
  __shared__ float As[32][36];
  __shared__ float Ws[32][64];
  const int t = threadIdx.x;
  const int brow = blockIdx.x * 32;
  const int bcol = blockIdx.y * 64;
  const int k0base = blockIdx.z * 128;
  C += (size_t)blockIdx.z * gridDim.x * 32 * ldc;  // split-K partial plane
  const int tx = t & 15, ty = t >> 4;
  const int ar = t >> 3, ak = (t & 7) * 4;
  float acc[2][4] = {};
  for (int c = 0; c < 4; ++c) {
    const int k0 = k0base + c * 32;
    *(float4*)&As[ar][ak] = *(const float4*)&A[(size_t)(brow + ar) * lda + k0 + ak];
#pragma unroll
    for (int q = 0; q < 2; ++q) {
      int i = t + q * 256;
      int k = i >> 4, c4 = (i & 15) * 4;
      *(float4*)&Ws[k][c4] = *(const float4*)&W[(size_t)(k0 + k) * ldw + bcol + c4];
    }
    __syncthreads();
#pragma unroll 2
    for (int kk = 0; kk < 32; kk += 4) {
      float4 a0 = *(const float4*)&As[ty * 2 + 0][kk];
      float4 a1 = *(const float4*)&As[ty * 2 + 1][kk];
#pragma unroll
      for (int j = 0; j < 4; ++j) {
        float4 w = *(const float4*)&Ws[kk + j][tx * 4];
        float av0 = ((const float*)&a0)[j];
        float av1 = ((const float*)&a1)[j];
        acc[0][0] = fmaf(av0, w.x, acc[0][0]);
        acc[0][1] = fmaf(av0, w.y, acc[0][1]);
        acc[0][2] = fmaf(av0, w.z, acc[0][2]);
        acc[0][3] = fmaf(av0, w.w, acc[0][3]);
        acc[1][0] = fmaf(av1, w.x, acc[1][0]);
        acc[1][1] = fmaf(av1, w.y, acc[1][1]);
        acc[1][2] = fmaf(av1, w.z, acc[1][2]);
        acc[1][3] = fmaf(av1, w.w, acc[1][3]);
      }
    }
    __syncthreads();
  }
#pragma unroll
  for (int r = 0; r < 2; ++r) {
    float4 o;
    o.x = acc[r][0]; o.y = acc[r][1]; o.z = acc[r][2]; o.w = acc[r][3];
    *(float4*)&C[(size_t)(brow + ty * 2 + r) * ldc + bcol + tx * 4] = o;
  }
}

// ---------------------------------------------------------------------------
// Sum 4 split-K partials + bias -> proj1, with fused scores1 (16-lane reduce).
// ---------------------------------------------------------------------------
__global__ __launch_bounds__(256) void reduce_scores1_kernel(
    const float* __restrict__ part, const float* __restrict__ bias,
    const float* __restrict__ a_src1, const float* __restrict__ a_tgt1,
    float* __restrict__ proj1, float* __restrict__ ssrc1,
    float* __restrict__ stgt1) {
  const int i = blockIdx.x * 256 + threadIdx.x;  // float4 idx, 65536 total
  const float4* p = (const float4*)part;
  float4 a = p[i], b = p[i + 65536], c = p[i + 131072], d = p[i + 196608];
  const int f4 = i & 15;
  const float4 bb = *(const float4*)&bias[f4 * 4];
  float4 r;
  r.x = a.x + b.x + c.x + d.x + bb.x;
  r.y = a.y + b.y + c.y + d.y + bb.y;
  r.z = a.z + b.z + c.z + d.z + bb.z;
  r.w = a.w + b.w + c.w + d.w + bb.w;
  ((float4*)proj1)[i] = r;
  const float4 as = *(const float4*)&a_src1[f4 * 4];
  const float4 at = *(const float4*)&a_tgt1[f4 * 4];
  float ps = r.x * as.x + r.y * as.y + r.z * as.z + r.w * as.w;
  float pt = r.x * at.x + r.y * at.y + r.z * at.z + r.w * at.w;
#pragma unroll
  for (int m = 8; m; m >>= 1) {
    ps += __shfl_xor(ps, m);
    pt += __shfl_xor(pt, m);
  }
  if (f4 == 0) {
    const int node = i >> 4;
    ssrc1[node] = ps;
    stgt1[node] = pt;
  }
}

// ---------------------------------------------------------------------------
// Sparse attention, H=8: softmax over edges (== masked dense softmax in fp32,
// exp(-1e9) underflows to 0); float4 gather with 2-way edge split.
// ---------------------------------------------------------------------------
__global__ __launch_bounds__(256) void attn8_kernel(
    const float* __restrict__ proj, const float* __restrict__ s_src,
    const float* __restrict__ s_tgt, const int* __restrict__ deg,
    const int* __restrict__ cols, float* __restrict__ out) {
  const int n = blockIdx.x;
  const int tid = threadIdx.x;
  __shared__ int sm_[CAP];
  __shared__ float sw[CAP * 8];
  __shared__ float sinv[8];
  __shared__ float4 buf[128];
  const int d = deg[n];
  for (int i = tid; i < d; i += 256) sm_[i] = cols[(size_t)n * CAP + i];
  __syncthreads();
  for (int i = tid; i < d * 8; i += 256) {
    int e = i >> 3, h = i & 7;
    float s = s_src[n * 8 + h] + s_tgt[sm_[e] * 8 + h];
    sw[i] = s >= 0.f ? s : 0.2f * s;
  }
  __syncthreads();
  const int lane = tid & 63, wid = tid >> 6;
  for (int h = wid; h < 8; h += 4) {  // 4 waves, 2 heads each
    float mx = -1e30f;
    for (int e = lane; e < d; e += 64) mx = fmaxf(mx, sw[e * 8 + h]);
#pragma unroll
    for (int o = 32; o; o >>= 1) mx = fmaxf(mx, __shfl_xor(mx, o));
    float sum = 0.f;
    for (int e = lane; e < d; e += 64) {
      float w = __expf(sw[e * 8 + h] - mx);
      sw[e * 8 + h] = w;
      sum += w;
    }
#pragma unroll
    for (int o = 32; o; o >>= 1) sum += __shfl_xor(sum, o);
    if (lane == 0) sinv[h] = 1.0f / sum;
  }
  __syncthreads();
  // gather: 128 float4 outputs, 2-way edge parallelism
  const int f4 = tid & 127, grp = tid >> 7;
  const int h = f4 >> 4;
  float4 acc = make_float4(0.f, 0.f, 0.f, 0.f);
  for (int e = grp; e < d; e += 2) {
    const float w = sw[e * 8 + h];
    const float4 pv = *(const float4*)&proj[(size_t)sm_[e] * 512 + f4 * 4];
    acc.x = fmaf(w, pv.x, acc.x);
    acc.y = fmaf(w, pv.y, acc.y);
    acc.z = fmaf(w, pv.z, acc.z);
    acc.w = fmaf(w, pv.w, acc.w);
  }
  if (grp == 1) buf[f4] = acc;
  __syncthreads();
  if (grp == 0) {
    const float4 o2 = buf[f4];
    const float s = sinv[h];
    float4 o;
    o.x = (acc.x + o2.x) * s;
    o.y = (acc.y + o2.y) * s;
    o.z = (acc.z + o2.z) * s;
    o.w = (acc.w + o2.w) * s;
    *(float4*)&out[(size_t)n * 512 + f4 * 4] = o;
  }
}

// ---------------------------------------------------------------------------
// Sparse attention, H=1: one wave per node; float4 gather, 4-way edge split.
// ---------------------------------------------------------------------------
__global__ void attn1_kernel(
    const float* __restrict__ proj, const float* __restrict__ s_src,
    const float* __restrict__ s_tgt, const int* __restrict__ deg,
    const int* __restrict__ cols, float* __restrict__ out) {
  const int n = blockIdx.x;
  const int tid = threadIdx.x;  // 64 threads = 1 wave
  __shared__ int sm_[CAP];
  __shared__ float sw[CAP];
  const int d = deg[n];
  for (int i = tid; i < d; i += 64) sm_[i] = cols[(size_t)n * CAP + i];
  __syncthreads();
  const float ssn = s_src[n];
  for (int i = tid; i < d; i += 64) {
    float s = ssn + s_tgt[sm_[i]];
    sw[i] = s >= 0.f ? s : 0.2f * s;
  }
  __syncthreads();
  float mx = -1e30f;
  for (int e = tid; e < d; e += 64) mx = fmaxf(mx, sw[e]);
#pragma unroll
  for (int o = 32; o; o >>= 1) mx = fmaxf(mx, __shfl_xor(mx, o));
  float sum = 0.f;
  for (int e = tid; e < d; e += 64) {
    float w = __expf(sw[e] - mx);
    sw[e] = w;
    sum += w;
  }
#pragma unroll
  for (int o = 32; o; o >>= 1) sum += __shfl_xor(sum, o);
  const float sinv = 1.0f / sum;
  __syncthreads();
  const int f4 = tid & 15, grp = tid >> 4;  // 16 float4 outputs, 4-way edges
  float4 acc = make_float4(0.f, 0.f, 0.f, 0.f);
  for (int e = grp; e < d; e += 4) {
    const float w = sw[e];
    const float4 pv = *(const float4*)&proj[(size_t)sm_[e] * 64 + f4 * 4];
    acc.x = fmaf(w, pv.x, acc.x);
    acc.y = fmaf(w, pv.y, acc.y);
    acc.z = fmaf(w, pv.z, acc.z);
    acc.w = fmaf(w, pv.w, acc.w);
  }
#pragma unroll
  for (int o = 16; o <= 32; o <<= 1) {
    acc.x += __shfl_xor(acc.x, o);
    acc.y += __shfl_xor(acc.y, o);
    acc.z += __shfl_xor(acc.z, o);
    acc.w += __shfl_xor(acc.w, o);
  }
  if (grp == 0) {
    acc.x *= sinv; acc.y *= sinv; acc.z *= sinv; acc.w *= sinv;
    *(float4*)&out[(size_t)n * 64 + f4 * 4] = acc;
  }
}

// ---------------------------------------------------------------------------
extern "C" void kernel_launch(void* const* d_in, const int* in_sizes, int n_in,
                              void* d_out, int out_size, void* d_ws, size_t ws_size,
                              hipStream_t stream) {
  const float* x      = (const float*)d_in[0];
  const float* mask   = (const float*)d_in[1];
  const float* W0     = (const float*)d_in[2];
  const float* b0     = (const float*)d_in[3];
  const float* a_src0 = (const float*)d_in[4];
  const float* a_tgt0 = (const float*)d_in[5];
  const float* W1     = (const float*)d_in[6];
  const float* b1     = (const float*)d_in[7];
  const float* a_src1 = (const float*)d_in[8];
  const float* a_tgt1 = (const float*)d_in[9];
  float* out = (float*)d_out;

  // workspace layout (~22.3 MB)
  float* ws    = (float*)d_ws;
  float* proj0 = ws;                          // 4096*512 (dead after attn8 -> reused as split-K partials)
  float* h0    = proj0 + NNODES * 512;        // 4096*512
  float* proj1 = h0 + NNODES * 512;           // 4096*64
  float* ssrc0 = proj1 + NNODES * 64;         // 4096*8
  float* stgt0 = ssrc0 + NNODES * 8;          // 4096*8
  float* ssrc1 = stgt0 + NNODES * 8;          // 4096
  float* stgt1 = ssrc1 + NNODES;              // 4096
  int* deg  = (int*)(stgt1 + NNODES);         // 4096
  int* cols = deg + NNODES;                   // 4096*CAP
  float* part = proj0;                        // 4*4096*64 aliases proj0 (dead by then)

  // phase 1: edge extraction (4096 blocks) overlapped with gemm0+scores0 (1024)
  phase1_kernel<<<NNODES + 1024, 256, 0, stream>>>(
      mask, deg, cols, x, W0, b0, a_src0, a_tgt0, proj0, ssrc0, stgt0);
  attn8_kernel<<<NNODES, 256, 0, stream>>>(proj0, ssrc0, stgt0, deg, cols, h0);

  // layer 1: K=512 split-K by 4, then fused reduce+bias+scores1
  gemm32x64_v2<<<dim3(NNODES / 32, 1, 4), 256, 0, stream>>>(
      h0, 512, W1, 64, part, 64);
  reduce_scores1_kernel<<<256, 256, 0, stream>>>(part, b1, a_src1, a_tgt1,
                                                 proj1, ssrc1, stgt1);
  attn1_kernel<<<NNODES, 64, 0, stream>>>(proj1, ssrc1, stgt1, deg, cols, out);
}